// Round 1
// baseline (2854.139 us; speedup 1.0000x reference)
//
#include <hip/hip_runtime.h>
#include <math.h>

#define NN 20000
#define NE 320000

// ---------------- CSR build ----------------

__global__ void k_zero_i32(int* __restrict__ p, int n) {
    int i = blockIdx.x * blockDim.x + threadIdx.x;
    if (i < n) p[i] = 0;
}

__global__ void k_count(const int* __restrict__ d0, const int* __restrict__ d1,
                        const int* __restrict__ d2, const int* __restrict__ d3,
                        int* __restrict__ cnt) {
    int i = blockIdx.x * blockDim.x + threadIdx.x;  // exactly 4*NE threads
    int g = i / NE, e = i - g * NE;
    const int* dp = (g == 0) ? d0 : (g == 1) ? d1 : (g == 2) ? d2 : d3;
    atomicAdd(&cnt[g * NN + dp[e]], 1);
}

// one block per graph; exclusive scan of cnt -> off, plus invdeg = 1/(deg+1)
__global__ void k_scan(const int* __restrict__ cnt, int* __restrict__ off,
                       float* __restrict__ iv) {
    const int g = blockIdx.x;
    const int* c = cnt + g * NN;
    int* o = off + g * (NN + 1);
    float* ivg = iv + g * NN;
    __shared__ int buf[1024];
    const int t = threadIdx.x;
    int carry = 0;
    for (int base = 0; base < NN; base += 1024) {
        int v = (base + t < NN) ? c[base + t] : 0;
        int run = v;
        buf[t] = run;
        __syncthreads();
        for (int s = 1; s < 1024; s <<= 1) {
            int add = (t >= s) ? buf[t - s] : 0;
            __syncthreads();
            run += add;
            buf[t] = run;
            __syncthreads();
        }
        if (base + t < NN) {
            o[base + t] = carry + run - v;
            ivg[base + t] = 1.0f / (float)(v + 1);
        }
        int tot = buf[1023];
        __syncthreads();
        carry += tot;
    }
    if (t == 0) o[NN] = carry;
}

__global__ void k_cursor(const int* __restrict__ off, int* __restrict__ cur) {
    int i = blockIdx.x * blockDim.x + threadIdx.x;
    if (i >= 4 * NN) return;
    int g = i / NN, n = i - g * NN;
    cur[i] = off[g * (NN + 1) + n];
}

__global__ void k_fill(const int* __restrict__ s0, const int* __restrict__ d0,
                       const int* __restrict__ s1, const int* __restrict__ d1,
                       const int* __restrict__ s2, const int* __restrict__ d2,
                       const int* __restrict__ s3, const int* __restrict__ d3,
                       int* __restrict__ cur, int* __restrict__ csr) {
    int i = blockIdx.x * blockDim.x + threadIdx.x;  // exactly 4*NE threads
    int g = i / NE, e = i - g * NE;
    const int* sp = (g == 0) ? s0 : (g == 1) ? s1 : (g == 2) ? s2 : s3;
    const int* dp = (g == 0) ? d0 : (g == 1) ? d1 : (g == 2) ? d2 : d3;
    int dst = dp[e];
    int p = atomicAdd(&cur[g * NN + dst], 1);
    csr[(size_t)g * NE + p] = sp[e];
}

// ---------------- small glue ----------------

__global__ void k_wt_softmax(const float* __restrict__ a, const float* __restrict__ b,
                             const float* __restrict__ c, const float* __restrict__ d,
                             float* __restrict__ wsm, float* __restrict__ owt) {
    int t = threadIdx.x;
    if (t >= 4) return;
    const float* p = (t == 0) ? a : (t == 1) ? b : (t == 2) ? c : d;
    float x0 = p[0], x1 = p[1], x2 = p[2];
    float m = fmaxf(x0, fmaxf(x1, x2));
    float e0 = expf(x0 - m), e1 = expf(x1 - m), e2 = expf(x2 - m);
    float inv = 1.0f / (e0 + e1 + e2);
    wsm[t * 3 + 0] = e0 * inv; wsm[t * 3 + 1] = e1 * inv; wsm[t * 3 + 2] = e2 * inv;
    owt[t * 3 + 0] = e0 * inv; owt[t * 3 + 1] = e1 * inv; owt[t * 3 + 2] = e2 * inv;
}

// ---------------- SpMM (mean aggregation, CSR, 1 wave per node) ----------------

__global__ void k_spmm(const int* __restrict__ off, const int* __restrict__ csr,
                       const float* __restrict__ invdeg, const float* __restrict__ x,
                       float* __restrict__ out, int dim) {
    int wid = (blockIdx.x * blockDim.x + threadIdx.x) >> 6;
    int lane = threadIdx.x & 63;
    if (wid >= NN) return;
    int e0 = off[wid], e1 = off[wid + 1];
    float sc = invdeg[wid];
    if (dim == 256) {
        const float4* xr = (const float4*)(x + (size_t)wid * 256);
        float4 acc = xr[lane];
        for (int e = e0; e < e1; ++e) {
            int s = csr[e];
            float4 v = ((const float4*)(x + (size_t)s * 256))[lane];
            acc.x += v.x; acc.y += v.y; acc.z += v.z; acc.w += v.w;
        }
        acc.x *= sc; acc.y *= sc; acc.z *= sc; acc.w *= sc;
        ((float4*)(out + (size_t)wid * 256))[lane] = acc;
    } else {  // dim == 128
        const float2* xr = (const float2*)(x + (size_t)wid * 128);
        float2 acc = xr[lane];
        for (int e = e0; e < e1; ++e) {
            int s = csr[e];
            float2 v = ((const float2*)(x + (size_t)s * 128))[lane];
            acc.x += v.x; acc.y += v.y;
        }
        acc.x *= sc; acc.y *= sc;
        ((float2*)(out + (size_t)wid * 128))[lane] = acc;
    }
}

// ---------------- fp32 tiled GEMM: C = A@W + bias, opt tanh, opt e (+)= w*C ----------------

__global__ __launch_bounds__(256) void k_gemm(
        const float* __restrict__ A, const float* __restrict__ W,
        const float* __restrict__ bias, float* __restrict__ C,
        int M, int Nn, int K, int act,
        float* __restrict__ eacc, const float* __restrict__ wsc, int emode) {
    __shared__ float As[16][64];
    __shared__ float Bs[16][64];
    const int t = threadIdx.x;
    const int tx = t & 15, ty = t >> 4;
    const int row0 = blockIdx.y << 6, col0 = blockIdx.x << 6;
    float acc[4][4] = {{0.f, 0.f, 0.f, 0.f}, {0.f, 0.f, 0.f, 0.f},
                       {0.f, 0.f, 0.f, 0.f}, {0.f, 0.f, 0.f, 0.f}};
    const int ar = t & 63, akq = (t >> 6) << 2;
    const int bk = t >> 4, bc = (t & 15) << 2;
    for (int k0 = 0; k0 < K; k0 += 16) {
        float4 av;
        const int arow = row0 + ar;
        if (arow < M) av = *(const float4*)(A + (size_t)arow * K + k0 + akq);
        else { av.x = av.y = av.z = av.w = 0.f; }
        As[akq + 0][ar] = av.x; As[akq + 1][ar] = av.y;
        As[akq + 2][ar] = av.z; As[akq + 3][ar] = av.w;
        *(float4*)&Bs[bk][bc] = *(const float4*)(W + (size_t)(k0 + bk) * Nn + col0 + bc);
        __syncthreads();
#pragma unroll
        for (int kk = 0; kk < 16; ++kk) {
            const float4 a4 = *(const float4*)&As[kk][ty << 2];
            const float4 b4 = *(const float4*)&Bs[kk][tx << 2];
            acc[0][0] += a4.x * b4.x; acc[0][1] += a4.x * b4.y;
            acc[0][2] += a4.x * b4.z; acc[0][3] += a4.x * b4.w;
            acc[1][0] += a4.y * b4.x; acc[1][1] += a4.y * b4.y;
            acc[1][2] += a4.y * b4.z; acc[1][3] += a4.y * b4.w;
            acc[2][0] += a4.z * b4.x; acc[2][1] += a4.z * b4.y;
            acc[2][2] += a4.z * b4.z; acc[2][3] += a4.z * b4.w;
            acc[3][0] += a4.w * b4.x; acc[3][1] += a4.w * b4.y;
            acc[3][2] += a4.w * b4.z; acc[3][3] += a4.w * b4.w;
        }
        __syncthreads();
    }
    float4 bb;
    if (bias) bb = *(const float4*)(bias + col0 + (tx << 2));
    else { bb.x = bb.y = bb.z = bb.w = 0.f; }
    const float wv = emode ? *wsc : 0.f;
#pragma unroll
    for (int i = 0; i < 4; ++i) {
        const int row = row0 + (ty << 2) + i;
        if (row >= M) continue;
        float4 v;
        v.x = acc[i][0] + bb.x; v.y = acc[i][1] + bb.y;
        v.z = acc[i][2] + bb.z; v.w = acc[i][3] + bb.w;
        if (act) { v.x = tanhf(v.x); v.y = tanhf(v.y); v.z = tanhf(v.z); v.w = tanhf(v.w); }
        *(float4*)(C + (size_t)row * Nn + col0 + (tx << 2)) = v;
        if (emode) {
            float* ep = eacc + (size_t)row * Nn + col0 + (tx << 2);
            if (emode == 1) {
                float4 ev; ev.x = v.x * wv; ev.y = v.y * wv; ev.z = v.z * wv; ev.w = v.w * wv;
                *(float4*)ep = ev;
            } else {
                float4 o = *(float4*)ep;
                o.x += v.x * wv; o.y += v.y * wv; o.z += v.z * wv; o.w += v.w * wv;
                *(float4*)ep = o;
            }
        }
    }
}

// ---------------- attention finalize (1 wave per node, H=128) ----------------

__global__ void k_attn_fin(const float* __restrict__ e1, const float* __restrict__ e2,
                           const float* __restrict__ v1, const float* __restrict__ v2,
                           const float* __restrict__ u, float* __restrict__ emb,
                           float* __restrict__ alpha) {
    int w = (blockIdx.x * blockDim.x + threadIdx.x) >> 6;
    int lane = threadIdx.x & 63;
    if (w >= NN) return;
    float2 uv = *(const float2*)(u + lane * 2);
    float2 a = *(const float2*)(v1 + (size_t)w * 128 + lane * 2);
    float2 b = *(const float2*)(v2 + (size_t)w * 128 + lane * 2);
    float d1 = a.x * uv.x + a.y * uv.y;
    float d2 = b.x * uv.x + b.y * uv.y;
    for (int s = 32; s > 0; s >>= 1) {
        d1 += __shfl_xor(d1, s, 64);
        d2 += __shfl_xor(d2, s, 64);
    }
    d1 += 1e-6f; d2 += 1e-6f;
    float m = fmaxf(d1, d2);
    float p1 = expf(d1 - m), p2 = expf(d2 - m);
    float inv = 1.0f / (p1 + p2);
    float al1 = p1 * inv, al2 = p2 * inv;
    float2 x1 = *(const float2*)(e1 + (size_t)w * 128 + lane * 2);
    float2 x2 = *(const float2*)(e2 + (size_t)w * 128 + lane * 2);
    float2 o;
    o.x = al1 * x1.x + al2 * x2.x;
    o.y = al1 * x1.y + al2 * x2.y;
    *(float2*)(emb + (size_t)w * 128 + lane * 2) = o;
    if (alpha != nullptr && lane == 0) {
        alpha[(size_t)w * 2 + 0] = al1;
        alpha[(size_t)w * 2 + 1] = al2;
    }
}

// ---------------- host ----------------

extern "C" void kernel_launch(void* const* d_in, const int* in_sizes, int n_in,
                              void* d_out, int out_size, void* d_ws, size_t ws_size,
                              hipStream_t stream) {
    (void)in_sizes; (void)n_in; (void)out_size; (void)ws_size;
    const int* esrc[4] = {(const int*)d_in[0], (const int*)d_in[2], (const int*)d_in[4], (const int*)d_in[6]};
    const int* edst[4] = {(const int*)d_in[1], (const int*)d_in[3], (const int*)d_in[5], (const int*)d_in[7]};
    const float* feat1 = (const float*)d_in[8];
    const float* feat2 = (const float*)d_in[9];
    const float* enc_W0[2] = {(const float*)d_in[10], (const float*)d_in[14]};
    const float* enc_b0[2] = {(const float*)d_in[11], (const float*)d_in[15]};
    const float* enc_W[2]  = {(const float*)d_in[12], (const float*)d_in[16]};
    const float* enc_b[2]  = {(const float*)d_in[13], (const float*)d_in[17]};
    const float* dec_W0[2] = {(const float*)d_in[18], (const float*)d_in[22]};
    const float* dec_b0[2] = {(const float*)d_in[19], (const float*)d_in[23]};
    const float* dec_W[2]  = {(const float*)d_in[20], (const float*)d_in[24]};
    const float* dec_b[2]  = {(const float*)d_in[21], (const float*)d_in[25]};
    const float* att_w[3]  = {(const float*)d_in[26], (const float*)d_in[28], (const float*)d_in[30]};
    const float* att_u[3]  = {(const float*)d_in[27], (const float*)d_in[29], (const float*)d_in[31]};
    const float* wt[4]     = {(const float*)d_in[32], (const float*)d_in[33], (const float*)d_in[34], (const float*)d_in[35]};

    float* out = (float*)d_out;
    float* O_embc = out;                    // [N,128]
    float* O_wt   = out + 2560000;          // [4,3]
    float* O_d1   = out + 2560012;          // [N,256]
    float* O_d2   = out + 7680012;          // [N,256]
    float* O_emb1 = out + 12800012;         // [N,128]
    float* O_emb2 = out + 15360012;         // [N,128]
    float* O_c1   = out + 17920012;         // [3,N,128]
    float* O_c2   = out + 25600012;         // [3,N,128]
    float* O_alph = out + 33280012;         // [N,2]

    // temporary residents inside cross output regions (dead until stage F)
    float* Esp1 = O_c1;
    float* Efe1 = O_c1 + 2560000;
    float* Esp2 = O_c1 + 5120000;
    float* Efe2 = O_c2;
    float* V1   = O_c2 + 2560000;
    float* V2   = O_c2 + 5120000;

    char* wp = (char*)d_ws;
    int* ws_off = (int*)wp;   wp += (size_t)4 * (NN + 1) * sizeof(int);   // 320016 B
    int* ws_csr = (int*)wp;   wp += (size_t)4 * NE * sizeof(int);         // 5.12 MB
    int* ws_cur = (int*)wp;   wp += (size_t)4 * NN * sizeof(int);         // 320 KB
    float* ws_iv = (float*)wp; wp += (size_t)4 * NN * sizeof(float);      // 320 KB
    float* ws_w  = (float*)wp; wp += 64;                                  // softmaxed wt[4][3]
    float* A = (float*)wp;     wp += (size_t)NN * 256 * sizeof(float);    // ping (20.48 MB)
    float* B = (float*)wp;     wp += (size_t)NN * 256 * sizeof(float);    // pong (20.48 MB)

    // ---- CSR build for the 4 graphs ----
    hipLaunchKernelGGL(k_zero_i32, dim3(313), dim3(256), 0, stream, ws_cur, 4 * NN);
    hipLaunchKernelGGL(k_count, dim3(5000), dim3(256), 0, stream,
                       edst[0], edst[1], edst[2], edst[3], ws_cur);
    hipLaunchKernelGGL(k_scan, dim3(4), dim3(1024), 0, stream, ws_cur, ws_off, ws_iv);
    hipLaunchKernelGGL(k_cursor, dim3(313), dim3(256), 0, stream, ws_off, ws_cur);
    hipLaunchKernelGGL(k_fill, dim3(5000), dim3(256), 0, stream,
                       esrc[0], edst[0], esrc[1], edst[1], esrc[2], edst[2], esrc[3], edst[3],
                       ws_cur, ws_csr);
    hipLaunchKernelGGL(k_wt_softmax, dim3(1), dim3(64), 0, stream,
                       wt[0], wt[1], wt[2], wt[3], ws_w, O_wt);

    auto spmm = [&](int g, const float* x, float* o, int dim) {
        hipLaunchKernelGGL(k_spmm, dim3(5000), dim3(256), 0, stream,
                           ws_off + g * (NN + 1), ws_csr + (size_t)g * NE, ws_iv + g * NN, x, o, dim);
    };
    auto gemm = [&](const float* Ain, const float* Wm, const float* bs, float* Cm,
                    int Nnn, int K, int act, float* ea, const float* wsc, int em) {
        hipLaunchKernelGGL(k_gemm, dim3(Nnn / 64, 313), dim3(256), 0, stream,
                           Ain, Wm, bs, Cm, NN, Nnn, K, act, ea, wsc, em);
    };
    auto afin = [&](const float* x1, const float* x2, const float* vv1, const float* vv2,
                    const float* uu, float* eo, float* al) {
        hipLaunchKernelGGL(k_attn_fin, dim3(5000), dim3(256), 0, stream,
                           x1, x2, vv1, vv2, uu, eo, al);
    };

    // ---- Stage B: 4 encoder runs with fused combine accumulation ----
    struct Run { int g; const float* f; int enc; float* e; int wi; };
    Run runs[4] = {{0, feat1, 0, Esp1, 0}, {1, feat1, 0, Efe1, 1},
                   {2, feat2, 1, Esp2, 2}, {3, feat2, 1, Efe2, 3}};
    for (int r = 0; r < 4; ++r) {
        Run& R = runs[r];
        spmm(R.g, R.f, A, 256);
        gemm(A, enc_W0[R.enc], enc_b0[R.enc], B, 128, 256, 0, R.e, ws_w + R.wi * 3 + 0, 1);
        spmm(R.g, B, A, 128);
        gemm(A, enc_W[R.enc], enc_b[R.enc], B, 128, 128, 0, R.e, ws_w + R.wi * 3 + 1, 2);
        spmm(R.g, B, A, 128);
        gemm(A, enc_W[R.enc] + 128 * 128, enc_b[R.enc] + 128, B, 128, 128, 0, R.e, ws_w + R.wi * 3 + 2, 2);
    }

    // ---- Stage D: attentions ----
    gemm(Esp1, att_w[0], nullptr, V1, 128, 128, 1, nullptr, nullptr, 0);
    gemm(Efe1, att_w[0], nullptr, V2, 128, 128, 1, nullptr, nullptr, 0);
    afin(Esp1, Efe1, V1, V2, att_u[0], O_emb1, nullptr);
    gemm(Esp2, att_w[1], nullptr, V1, 128, 128, 1, nullptr, nullptr, 0);
    gemm(Efe2, att_w[1], nullptr, V2, 128, 128, 1, nullptr, nullptr, 0);
    afin(Esp2, Efe2, V1, V2, att_u[1], O_emb2, nullptr);
    gemm(O_emb1, att_w[2], nullptr, V1, 128, 128, 1, nullptr, nullptr, 0);
    gemm(O_emb2, att_w[2], nullptr, V2, 128, 128, 1, nullptr, nullptr, 0);
    afin(O_emb1, O_emb2, V1, V2, att_u[2], O_embc, O_alph);

    // ---- Stage E: decoders d1, d2 (both on graph e1s, input emb_comb) ----
    for (int dsel = 0; dsel < 2; ++dsel) {
        float* od = (dsel == 0) ? O_d1 : O_d2;
        spmm(0, O_embc, A, 128);
        gemm(A, dec_W0[dsel], dec_b0[dsel], B, 256, 128, 0, nullptr, nullptr, 0);
        spmm(0, B, A, 256);
        gemm(A, dec_W[dsel], dec_b[dsel], B, 256, 256, 0, nullptr, nullptr, 0);
        spmm(0, B, A, 256);
        gemm(A, dec_W[dsel] + 256 * 256, dec_b[dsel] + 256, od, 256, 256, 0, nullptr, nullptr, 0);
    }

    // ---- Stage F: cross1 = enc2(e1s, dec2(e1s, emb1)); cross2 = enc1(e2s, dec1(e2s, emb2)) ----
    for (int c = 0; c < 2; ++c) {
        int g = (c == 0) ? 0 : 2;
        int dsel = (c == 0) ? 1 : 0;
        int enc = (c == 0) ? 1 : 0;
        const float* inp = (c == 0) ? O_emb1 : O_emb2;
        float* oc = (c == 0) ? O_c1 : O_c2;
        spmm(g, inp, A, 128);
        gemm(A, dec_W0[dsel], dec_b0[dsel], B, 256, 128, 0, nullptr, nullptr, 0);
        spmm(g, B, A, 256);
        gemm(A, dec_W[dsel], dec_b[dsel], B, 256, 256, 0, nullptr, nullptr, 0);
        spmm(g, B, A, 256);
        gemm(A, dec_W[dsel] + 256 * 256, dec_b[dsel] + 256, B, 256, 256, 0, nullptr, nullptr, 0);
        // encoder stack written straight into the cross output region
        spmm(g, B, A, 256);
        gemm(A, enc_W0[enc], enc_b0[enc], oc, 128, 256, 0, nullptr, nullptr, 0);
        spmm(g, oc, A, 128);
        gemm(A, enc_W[enc], enc_b[enc], oc + 2560000, 128, 128, 0, nullptr, nullptr, 0);
        spmm(g, oc + 2560000, A, 128);
        gemm(A, enc_W[enc] + 128 * 128, enc_b[enc] + 128, oc + 5120000, 128, 128, 0, nullptr, nullptr, 0);
    }
}

// Round 2
// 2166.601 us; speedup vs baseline: 1.3173x; 1.3173x over previous
//
#include <hip/hip_runtime.h>
#include <math.h>

#define NN 20000
#define NE 320000

typedef _Float16 v8h __attribute__((ext_vector_type(8)));
typedef _Float16 v4h __attribute__((ext_vector_type(4)));
typedef _Float16 v2h __attribute__((ext_vector_type(2)));
typedef float v4f __attribute__((ext_vector_type(4)));

// ---------------- CSR build ----------------

__global__ void k_zero_i32(int* __restrict__ p, int n) {
    int i = blockIdx.x * blockDim.x + threadIdx.x;
    if (i < n) p[i] = 0;
}

__global__ void k_count(const int* __restrict__ d0, const int* __restrict__ d1,
                        const int* __restrict__ d2, const int* __restrict__ d3,
                        int* __restrict__ cnt) {
    int i = blockIdx.x * blockDim.x + threadIdx.x;
    int g = i / NE, e = i - g * NE;
    const int* dp = (g == 0) ? d0 : (g == 1) ? d1 : (g == 2) ? d2 : d3;
    atomicAdd(&cnt[g * NN + dp[e]], 1);
}

__global__ void k_scan(const int* __restrict__ cnt, int* __restrict__ off,
                       float* __restrict__ iv) {
    const int g = blockIdx.x;
    const int* c = cnt + g * NN;
    int* o = off + g * (NN + 1);
    float* ivg = iv + g * NN;
    __shared__ int buf[1024];
    const int t = threadIdx.x;
    int carry = 0;
    for (int base = 0; base < NN; base += 1024) {
        int v = (base + t < NN) ? c[base + t] : 0;
        int run = v;
        buf[t] = run;
        __syncthreads();
        for (int s = 1; s < 1024; s <<= 1) {
            int add = (t >= s) ? buf[t - s] : 0;
            __syncthreads();
            run += add;
            buf[t] = run;
            __syncthreads();
        }
        if (base + t < NN) {
            o[base + t] = carry + run - v;
            ivg[base + t] = 1.0f / (float)(v + 1);
        }
        int tot = buf[1023];
        __syncthreads();
        carry += tot;
    }
    if (t == 0) o[NN] = carry;
}

__global__ void k_cursor(const int* __restrict__ off, int* __restrict__ cur) {
    int i = blockIdx.x * blockDim.x + threadIdx.x;
    if (i >= 4 * NN) return;
    int g = i / NN, n = i - g * NN;
    cur[i] = off[g * (NN + 1) + n];
}

__global__ void k_fill(const int* __restrict__ s0, const int* __restrict__ d0,
                       const int* __restrict__ s1, const int* __restrict__ d1,
                       const int* __restrict__ s2, const int* __restrict__ d2,
                       const int* __restrict__ s3, const int* __restrict__ d3,
                       int* __restrict__ cur, int* __restrict__ csr) {
    int i = blockIdx.x * blockDim.x + threadIdx.x;
    int g = i / NE, e = i - g * NE;
    const int* sp = (g == 0) ? s0 : (g == 1) ? s1 : (g == 2) ? s2 : s3;
    const int* dp = (g == 0) ? d0 : (g == 1) ? d1 : (g == 2) ? d2 : d3;
    int dst = dp[e];
    int p = atomicAdd(&cur[g * NN + dst], 1);
    csr[(size_t)g * NE + p] = sp[e];
}

// ---------------- small glue ----------------

__global__ void k_wt_softmax(const float* __restrict__ a, const float* __restrict__ b,
                             const float* __restrict__ c, const float* __restrict__ d,
                             float* __restrict__ wsm, float* __restrict__ owt) {
    int t = threadIdx.x;
    if (t >= 4) return;
    const float* p = (t == 0) ? a : (t == 1) ? b : (t == 2) ? c : d;
    float x0 = p[0], x1 = p[1], x2 = p[2];
    float m = fmaxf(x0, fmaxf(x1, x2));
    float e0 = expf(x0 - m), e1 = expf(x1 - m), e2 = expf(x2 - m);
    float inv = 1.0f / (e0 + e1 + e2);
    wsm[t * 3 + 0] = e0 * inv; wsm[t * 3 + 1] = e1 * inv; wsm[t * 3 + 2] = e2 * inv;
    owt[t * 3 + 0] = e0 * inv; owt[t * 3 + 1] = e1 * inv; owt[t * 3 + 2] = e2 * inv;
}

// f32 -> f16 elementwise (float4 granularity)
__global__ void k_cvt16(const float* __restrict__ in, _Float16* __restrict__ out, int n4) {
    int i = blockIdx.x * blockDim.x + threadIdx.x;
    if (i >= n4) return;
    float4 v = ((const float4*)in)[i];
    v4h o; o[0] = (_Float16)v.x; o[1] = (_Float16)v.y; o[2] = (_Float16)v.z; o[3] = (_Float16)v.w;
    ((v4h*)out)[i] = o;
}

// ---------------- weight prep: transpose [K][N] f32 -> [N][K] f16 ----------------

struct PWArgs { const float* s[15]; };

__global__ __launch_bounds__(256) void k_prepW(PWArgs pa, _Float16* __restrict__ dst) {
    const int wK[15]   = {256,128,128,256,128,128, 128,256,256, 128,256,256, 128,128,128};
    const int wN[15]   = {128,128,128,128,128,128, 256,256,256, 256,256,256, 128,128,128};
    const int wOff[15] = {0,32768,49152,65536,98304,114688,
                          131072,163840,229376, 294912,327680,393216,
                          458752,475136,491520};
    int b = blockIdx.x, w = 0, start = 0;
    for (w = 0; w < 15; ++w) {
        int t = (wK[w] / 64) * (wN[w] / 64);
        if (b < start + t) break;
        start += t;
    }
    const int K = wK[w], N = wN[w];
    const int lt = b - start;
    const int nt = N / 64;
    const int k0 = (lt / nt) * 64, n0 = (lt % nt) * 64;
    const float* src = pa.s[w];
    __shared__ float T[64][65];
    const int t = threadIdx.x;
    const int c4 = (t & 15) * 4;
#pragma unroll
    for (int j = 0; j < 4; ++j) {
        int row = (t >> 4) + 16 * j;  // k-dim
        float4 v = *(const float4*)(src + (size_t)(k0 + row) * N + n0 + c4);
        T[row][c4 + 0] = v.x; T[row][c4 + 1] = v.y; T[row][c4 + 2] = v.z; T[row][c4 + 3] = v.w;
    }
    __syncthreads();
#pragma unroll
    for (int j = 0; j < 4; ++j) {
        int r = (t >> 4) + 16 * j;  // n-dim
        v4h o;
#pragma unroll
        for (int i = 0; i < 4; ++i) o[i] = (_Float16)T[c4 + i][r];
        *(v4h*)(dst + wOff[w] + (size_t)(n0 + r) * K + k0 + c4) = o;
    }
}

// ---------------- SpMM f16 (mean agg, CSR, 1 wave/node) + fused epilogue ----------------
// out = (x[i] + sum_j x[j]) * iv  (+ bias);  optional o16/o32;  optional E accumulate.

template<int DIM>
__global__ void k_spmm(const int* __restrict__ off, const int* __restrict__ csr,
                       const float* __restrict__ iv, const _Float16* __restrict__ x,
                       const float* __restrict__ bias,
                       _Float16* __restrict__ o16, float* __restrict__ o32,
                       _Float16* __restrict__ E, const float* __restrict__ wsc, int emode) {
    int wid = (blockIdx.x * blockDim.x + threadIdx.x) >> 6;
    int lane = threadIdx.x & 63;
    if (wid >= NN) return;
    int e0 = off[wid], e1 = off[wid + 1];
    float sc = iv[wid];
    if (DIM == 256) {
        const int c0 = lane * 4;
        v4h s = *(const v4h*)(x + (size_t)wid * 256 + c0);
        float a0 = (float)s[0], a1 = (float)s[1], a2 = (float)s[2], a3 = (float)s[3];
        for (int e = e0; e < e1; ++e) {
            int sidx = csr[e];
            v4h v = *(const v4h*)(x + (size_t)sidx * 256 + c0);
            a0 += (float)v[0]; a1 += (float)v[1]; a2 += (float)v[2]; a3 += (float)v[3];
        }
        a0 *= sc; a1 *= sc; a2 *= sc; a3 *= sc;
        if (bias) { a0 += bias[c0]; a1 += bias[c0 + 1]; a2 += bias[c0 + 2]; a3 += bias[c0 + 3]; }
        if (o16) {
            v4h o; o[0] = (_Float16)a0; o[1] = (_Float16)a1; o[2] = (_Float16)a2; o[3] = (_Float16)a3;
            *(v4h*)(o16 + (size_t)wid * 256 + c0) = o;
        }
        if (o32) {
            float4 o; o.x = a0; o.y = a1; o.z = a2; o.w = a3;
            *(float4*)(o32 + (size_t)wid * 256 + c0) = o;
        }
    } else {
        const int c0 = lane * 2;
        v2h s = *(const v2h*)(x + (size_t)wid * 128 + c0);
        float a0 = (float)s[0], a1 = (float)s[1];
        for (int e = e0; e < e1; ++e) {
            int sidx = csr[e];
            v2h v = *(const v2h*)(x + (size_t)sidx * 128 + c0);
            a0 += (float)v[0]; a1 += (float)v[1];
        }
        a0 *= sc; a1 *= sc;
        if (bias) { a0 += bias[c0]; a1 += bias[c0 + 1]; }
        if (o16) {
            v2h o; o[0] = (_Float16)a0; o[1] = (_Float16)a1;
            *(v2h*)(o16 + (size_t)wid * 128 + c0) = o;
        }
        if (o32) {
            float2 o; o.x = a0; o.y = a1;
            *(float2*)(o32 + (size_t)wid * 128 + c0) = o;
        }
        if (emode) {
            float wv = *wsc;
            _Float16* ep = E + (size_t)wid * 128 + c0;
            if (emode == 1) {
                v2h o; o[0] = (_Float16)(a0 * wv); o[1] = (_Float16)(a1 * wv);
                *(v2h*)ep = o;
            } else {
                v2h old = *(v2h*)ep;
                v2h o; o[0] = (_Float16)((float)old[0] + a0 * wv);
                o[1] = (_Float16)((float)old[1] + a1 * wv);
                *(v2h*)ep = o;
            }
        }
    }
}

// ---------------- MFMA fp16 GEMM (LDS-free): C = A@W^T_t + bias ----------------
// A: [M][K] f16, Wt: [N][K] f16 (pre-transposed). Block = 4 waves; wave = 32 rows x 128 cols.
// Fragment maps (CDNA4 16x16x32): A: row=l&15, k=8*(l>>4)+i ; B: col=l&15, same k ;
// D: col=l&15, row=4*(l>>4)+i   [m89-verified C/D layout]

template<int K>
__global__ __launch_bounds__(256) void k_gemm(const _Float16* __restrict__ A,
        const _Float16* __restrict__ Wt, const float* __restrict__ bias,
        int Ntot, int act,
        _Float16* __restrict__ C16, float* __restrict__ C32,
        _Float16* __restrict__ E, const float* __restrict__ wsc, int emode) {
    const int wid = threadIdx.x >> 6, l = threadIdx.x & 63;
    const int r0 = (blockIdx.y * 4 + wid) * 32;
    if (r0 >= NN) return;
    const int colbase = blockIdx.x * 128;
    const int lr = l & 15, lg = l >> 4;
    v4f acc[2][8];
#pragma unroll
    for (int m = 0; m < 2; ++m)
#pragma unroll
        for (int n = 0; n < 8; ++n) acc[m][n] = (v4f){0.f, 0.f, 0.f, 0.f};

    const _Float16* Ab = A + (size_t)(r0 + lr) * K + 8 * lg;
    const _Float16* Wb = Wt + (size_t)(colbase + lr) * K + 8 * lg;
    constexpr int KS = K / 32;
#pragma unroll
    for (int k = 0; k < KS; ++k) {
        v8h a0 = *(const v8h*)(Ab + k * 32);
        v8h a1 = *(const v8h*)(Ab + (size_t)16 * K + k * 32);
        v8h b0 = *(const v8h*)(Wb + k * 32);
        v8h b1 = *(const v8h*)(Wb + (size_t)16 * K + k * 32);
        v8h b2 = *(const v8h*)(Wb + (size_t)32 * K + k * 32);
        v8h b3 = *(const v8h*)(Wb + (size_t)48 * K + k * 32);
        v8h b4 = *(const v8h*)(Wb + (size_t)64 * K + k * 32);
        v8h b5 = *(const v8h*)(Wb + (size_t)80 * K + k * 32);
        v8h b6 = *(const v8h*)(Wb + (size_t)96 * K + k * 32);
        v8h b7 = *(const v8h*)(Wb + (size_t)112 * K + k * 32);
        acc[0][0] = __builtin_amdgcn_mfma_f32_16x16x32_f16(a0, b0, acc[0][0], 0, 0, 0);
        acc[0][1] = __builtin_amdgcn_mfma_f32_16x16x32_f16(a0, b1, acc[0][1], 0, 0, 0);
        acc[0][2] = __builtin_amdgcn_mfma_f32_16x16x32_f16(a0, b2, acc[0][2], 0, 0, 0);
        acc[0][3] = __builtin_amdgcn_mfma_f32_16x16x32_f16(a0, b3, acc[0][3], 0, 0, 0);
        acc[0][4] = __builtin_amdgcn_mfma_f32_16x16x32_f16(a0, b4, acc[0][4], 0, 0, 0);
        acc[0][5] = __builtin_amdgcn_mfma_f32_16x16x32_f16(a0, b5, acc[0][5], 0, 0, 0);
        acc[0][6] = __builtin_amdgcn_mfma_f32_16x16x32_f16(a0, b6, acc[0][6], 0, 0, 0);
        acc[0][7] = __builtin_amdgcn_mfma_f32_16x16x32_f16(a0, b7, acc[0][7], 0, 0, 0);
        acc[1][0] = __builtin_amdgcn_mfma_f32_16x16x32_f16(a1, b0, acc[1][0], 0, 0, 0);
        acc[1][1] = __builtin_amdgcn_mfma_f32_16x16x32_f16(a1, b1, acc[1][1], 0, 0, 0);
        acc[1][2] = __builtin_amdgcn_mfma_f32_16x16x32_f16(a1, b2, acc[1][2], 0, 0, 0);
        acc[1][3] = __builtin_amdgcn_mfma_f32_16x16x32_f16(a1, b3, acc[1][3], 0, 0, 0);
        acc[1][4] = __builtin_amdgcn_mfma_f32_16x16x32_f16(a1, b4, acc[1][4], 0, 0, 0);
        acc[1][5] = __builtin_amdgcn_mfma_f32_16x16x32_f16(a1, b5, acc[1][5], 0, 0, 0);
        acc[1][6] = __builtin_amdgcn_mfma_f32_16x16x32_f16(a1, b6, acc[1][6], 0, 0, 0);
        acc[1][7] = __builtin_amdgcn_mfma_f32_16x16x32_f16(a1, b7, acc[1][7], 0, 0, 0);
    }

    const float wv = emode ? *wsc : 0.f;
#pragma unroll
    for (int m = 0; m < 2; ++m) {
#pragma unroll
        for (int n = 0; n < 8; ++n) {
            const int col = colbase + n * 16 + lr;
            const float bv = bias ? bias[col] : 0.f;
#pragma unroll
            for (int i = 0; i < 4; ++i) {
                const int row = r0 + m * 16 + 4 * lg + i;
                float v = acc[m][n][i] + bv;
                if (act) v = tanhf(v);
                if (C32) C32[(size_t)row * Ntot + col] = v;
                if (C16) C16[(size_t)row * Ntot + col] = (_Float16)v;
                if (emode) {
                    _Float16* ep = E + (size_t)row * 128 + col;
                    if (emode == 1) *ep = (_Float16)(v * wv);
                    else *ep = (_Float16)((float)*ep + v * wv);
                }
            }
        }
    }
}

// ---------------- attention finalize (f16 in, 1 wave/node, H=128) ----------------

__global__ void k_attn_fin(const _Float16* __restrict__ e1, const _Float16* __restrict__ e2,
                           const _Float16* __restrict__ v1, const _Float16* __restrict__ v2,
                           const float* __restrict__ u, float* __restrict__ emb32,
                           _Float16* __restrict__ emb16, float* __restrict__ alpha) {
    int w = (blockIdx.x * blockDim.x + threadIdx.x) >> 6;
    int lane = threadIdx.x & 63;
    if (w >= NN) return;
    const int c0 = lane * 2;
    float2 uv = *(const float2*)(u + c0);
    v2h a = *(const v2h*)(v1 + (size_t)w * 128 + c0);
    v2h b = *(const v2h*)(v2 + (size_t)w * 128 + c0);
    float d1 = (float)a[0] * uv.x + (float)a[1] * uv.y;
    float d2 = (float)b[0] * uv.x + (float)b[1] * uv.y;
    for (int s = 32; s > 0; s >>= 1) {
        d1 += __shfl_xor(d1, s, 64);
        d2 += __shfl_xor(d2, s, 64);
    }
    d1 += 1e-6f; d2 += 1e-6f;
    float m = fmaxf(d1, d2);
    float p1 = expf(d1 - m), p2 = expf(d2 - m);
    float inv = 1.0f / (p1 + p2);
    float al1 = p1 * inv, al2 = p2 * inv;
    v2h x1 = *(const v2h*)(e1 + (size_t)w * 128 + c0);
    v2h x2 = *(const v2h*)(e2 + (size_t)w * 128 + c0);
    float o0 = al1 * (float)x1[0] + al2 * (float)x2[0];
    float o1 = al1 * (float)x1[1] + al2 * (float)x2[1];
    float2 o; o.x = o0; o.y = o1;
    *(float2*)(emb32 + (size_t)w * 128 + c0) = o;
    v2h oh; oh[0] = (_Float16)o0; oh[1] = (_Float16)o1;
    *(v2h*)(emb16 + (size_t)w * 128 + c0) = oh;
    if (alpha != nullptr && lane == 0) {
        alpha[(size_t)w * 2 + 0] = al1;
        alpha[(size_t)w * 2 + 1] = al2;
    }
}

// ---------------- host ----------------

static inline char* alignup(char* p, size_t a) {
    return (char*)(((uintptr_t)p + a - 1) & ~(uintptr_t)(a - 1));
}

extern "C" void kernel_launch(void* const* d_in, const int* in_sizes, int n_in,
                              void* d_out, int out_size, void* d_ws, size_t ws_size,
                              hipStream_t stream) {
    (void)in_sizes; (void)n_in; (void)out_size; (void)ws_size;
    const int* esrc[4] = {(const int*)d_in[0], (const int*)d_in[2], (const int*)d_in[4], (const int*)d_in[6]};
    const int* edst[4] = {(const int*)d_in[1], (const int*)d_in[3], (const int*)d_in[5], (const int*)d_in[7]};
    const float* feat1 = (const float*)d_in[8];
    const float* feat2 = (const float*)d_in[9];
    const float* enc_W0[2] = {(const float*)d_in[10], (const float*)d_in[14]};
    const float* enc_b0[2] = {(const float*)d_in[11], (const float*)d_in[15]};
    const float* enc_W[2]  = {(const float*)d_in[12], (const float*)d_in[16]};
    const float* enc_b[2]  = {(const float*)d_in[13], (const float*)d_in[17]};
    const float* dec_W0[2] = {(const float*)d_in[18], (const float*)d_in[22]};
    const float* dec_b0[2] = {(const float*)d_in[19], (const float*)d_in[23]};
    const float* dec_W[2]  = {(const float*)d_in[20], (const float*)d_in[24]};
    const float* dec_b[2]  = {(const float*)d_in[21], (const float*)d_in[25]};
    const float* att_w[3]  = {(const float*)d_in[26], (const float*)d_in[28], (const float*)d_in[30]};
    const float* att_u[3]  = {(const float*)d_in[27], (const float*)d_in[29], (const float*)d_in[31]};
    const float* wt[4]     = {(const float*)d_in[32], (const float*)d_in[33], (const float*)d_in[34], (const float*)d_in[35]};

    float* out = (float*)d_out;
    float* O_embc = out;                    // [N,128]
    float* O_wt   = out + 2560000;          // [4,3]
    float* O_d1   = out + 2560012;          // [N,256]
    float* O_d2   = out + 7680012;          // [N,256]
    float* O_emb1 = out + 12800012;         // [N,128]
    float* O_emb2 = out + 15360012;         // [N,128]
    float* O_c1   = out + 17920012;         // [3,N,128]
    float* O_c2   = out + 25600012;         // [3,N,128]
    float* O_alph = out + 33280012;         // [N,2]

    // f16 temporaries living in dead output regions (stages B-D only)
    _Float16* E1 = (_Float16*)O_c1;                 // e_sp1
    _Float16* E2 = E1 + (size_t)NN * 128;           // e_fe1
    _Float16* E3 = E2 + (size_t)NN * 128;           // e_sp2
    _Float16* E4 = E3 + (size_t)NN * 128;           // e_fe2  (20.5MB of 30.7MB O_c1)
    _Float16* V1 = (_Float16*)O_c2;
    _Float16* V2 = V1 + (size_t)NN * 128;
    _Float16* Xe = (_Float16*)O_c1;                 // stage-E dim256 scratch (E* dead by then)

    // workspace
    char* wp = (char*)d_ws;
    int* ws_off = (int*)wp;    wp += (size_t)4 * (NN + 1) * sizeof(int); wp = alignup(wp, 64);
    int* ws_csr = (int*)wp;    wp += (size_t)4 * NE * sizeof(int);
    int* ws_cur = (int*)wp;    wp += (size_t)4 * NN * sizeof(int);
    float* ws_iv = (float*)wp; wp += (size_t)4 * NN * sizeof(float);
    float* ws_w  = (float*)wp; wp += 64;
    _Float16* Wt = (_Float16*)wp; wp += (size_t)507904 * 2; wp = alignup(wp, 64);
    _Float16* F1 = (_Float16*)wp; wp += (size_t)NN * 256 * 2;  // feat1_f16 -> stageB scratch -> embc16/emb1_16
    _Float16* F2 = (_Float16*)wp; wp += (size_t)NN * 256 * 2;  // feat2_f16 -> emb2_16
    _Float16* Abuf = (_Float16*)wp; wp += (size_t)NN * 256 * 2;
    _Float16* Bbuf = (_Float16*)wp; wp += (size_t)NN * 256 * 2;

    _Float16* XB = F1;                          // stage-B dim128 scratch (feat1 dead after P1)
    _Float16* embc16 = F1;                      // stage D+: F1 free
    _Float16* emb1_16 = F1 + (size_t)NN * 128;
    _Float16* emb2_16 = F2;

    // Wt segment offsets (elems)
    const int oEnc1W0 = 0, oEnc1W1 = 32768, oEnc1W2 = 49152;
    const int oEnc2W0 = 65536, oEnc2W1 = 98304, oEnc2W2 = 114688;
    const int oDec1W0 = 131072, oDec1W1 = 163840, oDec1W2 = 229376;
    const int oDec2W0 = 294912, oDec2W1 = 327680, oDec2W2 = 393216;
    const int oAtt1 = 458752, oAtt2 = 475136, oAttc = 491520;
    const int oEncW0[2] = {oEnc1W0, oEnc2W0};
    const int oEncW1[2] = {oEnc1W1, oEnc2W1};
    const int oEncW2[2] = {oEnc1W2, oEnc2W2};
    const int oDecW0[2] = {oDec1W0, oDec2W0};
    const int oDecW1[2] = {oDec1W1, oDec2W1};
    const int oDecW2[2] = {oDec1W2, oDec2W2};

    // ---- CSR build ----
    hipLaunchKernelGGL(k_zero_i32, dim3(313), dim3(256), 0, stream, ws_cur, 4 * NN);
    hipLaunchKernelGGL(k_count, dim3(5000), dim3(256), 0, stream,
                       edst[0], edst[1], edst[2], edst[3], ws_cur);
    hipLaunchKernelGGL(k_scan, dim3(4), dim3(1024), 0, stream, ws_cur, ws_off, ws_iv);
    hipLaunchKernelGGL(k_cursor, dim3(313), dim3(256), 0, stream, ws_off, ws_cur);
    hipLaunchKernelGGL(k_fill, dim3(5000), dim3(256), 0, stream,
                       esrc[0], edst[0], esrc[1], edst[1], esrc[2], edst[2], esrc[3], edst[3],
                       ws_cur, ws_csr);
    hipLaunchKernelGGL(k_wt_softmax, dim3(1), dim3(64), 0, stream,
                       wt[0], wt[1], wt[2], wt[3], ws_w, O_wt);

    // ---- weight + feature conversion ----
    PWArgs pa;
    pa.s[0] = enc_W0[0]; pa.s[1] = enc_W[0]; pa.s[2] = enc_W[0] + 16384;
    pa.s[3] = enc_W0[1]; pa.s[4] = enc_W[1]; pa.s[5] = enc_W[1] + 16384;
    pa.s[6] = dec_W0[0]; pa.s[7] = dec_W[0]; pa.s[8] = dec_W[0] + 65536;
    pa.s[9] = dec_W0[1]; pa.s[10] = dec_W[1]; pa.s[11] = dec_W[1] + 65536;
    pa.s[12] = att_w[0]; pa.s[13] = att_w[1]; pa.s[14] = att_w[2];
    hipLaunchKernelGGL(k_prepW, dim3(124), dim3(256), 0, stream, pa, Wt);
    hipLaunchKernelGGL(k_cvt16, dim3(5000), dim3(256), 0, stream, feat1, F1, NN * 64);
    hipLaunchKernelGGL(k_cvt16, dim3(5000), dim3(256), 0, stream, feat2, F2, NN * 64);

    auto spmm128 = [&](int g, const _Float16* x, const float* bias, _Float16* o16, float* o32,
                       _Float16* E, const float* wsc, int em) {
        hipLaunchKernelGGL(k_spmm<128>, dim3(5000), dim3(256), 0, stream,
                           ws_off + g * (NN + 1), ws_csr + (size_t)g * NE, ws_iv + g * NN,
                           x, bias, o16, o32, E, wsc, em);
    };
    auto spmm256 = [&](int g, const _Float16* x, _Float16* o16) {
        hipLaunchKernelGGL(k_spmm<256>, dim3(5000), dim3(256), 0, stream,
                           ws_off + g * (NN + 1), ws_csr + (size_t)g * NE, ws_iv + g * NN,
                           x, nullptr, o16, nullptr, nullptr, nullptr, 0);
    };
    auto gemm128 = [&](const _Float16* A, int wtoff, const float* bias, int Ntot, int act,
                       _Float16* C16, float* C32, _Float16* E, const float* wsc, int em) {
        hipLaunchKernelGGL(k_gemm<128>, dim3(Ntot / 128, 157), dim3(256), 0, stream,
                           A, Wt + wtoff, bias, Ntot, act, C16, C32, E, wsc, em);
    };
    auto gemm256 = [&](const _Float16* A, int wtoff, const float* bias, int Ntot, int act,
                       _Float16* C16, float* C32, _Float16* E, const float* wsc, int em) {
        hipLaunchKernelGGL(k_gemm<256>, dim3(Ntot / 128, 157), dim3(256), 0, stream,
                           A, Wt + wtoff, bias, Ntot, act, C16, C32, E, wsc, em);
    };
    auto afin = [&](const _Float16* x1, const _Float16* x2, const _Float16* vv1, const _Float16* vv2,
                    const float* uu, float* eo32, _Float16* eo16, float* al) {
        hipLaunchKernelGGL(k_attn_fin, dim3(5000), dim3(256), 0, stream,
                           x1, x2, vv1, vv2, uu, eo32, eo16, al);
    };

    // ---- Stage B: encoders with project-first L1 + fused combine ----
    // P1 = feat1 @ enc1_W0 (shared by graphs 0,1)
    gemm256(F1, oEnc1W0, nullptr, 128, 0, Abuf, nullptr, nullptr, nullptr, 0);
    {
        struct Run { int g; _Float16* E; int wi; };
        Run runs[2] = {{0, E1, 0}, {1, E2, 1}};
        for (int r = 0; r < 2; ++r) {
            spmm128(runs[r].g, Abuf, enc_b0[0], Bbuf, nullptr, runs[r].E, ws_w + runs[r].wi * 3 + 0, 1);
            spmm128(runs[r].g, Bbuf, nullptr, XB, nullptr, nullptr, nullptr, 0);
            gemm128(XB, oEnc1W1, enc_b[0], 128, 0, Bbuf, nullptr, runs[r].E, ws_w + runs[r].wi * 3 + 1, 2);
            spmm128(runs[r].g, Bbuf, nullptr, XB, nullptr, nullptr, nullptr, 0);
            gemm128(XB, oEnc1W2, enc_b[0] + 128, 128, 0, nullptr, nullptr, runs[r].E, ws_w + runs[r].wi * 3 + 2, 2);
        }
    }
    // P2 = feat2 @ enc2_W0 (graphs 2,3)
    gemm256(F2, oEnc2W0, nullptr, 128, 0, Abuf, nullptr, nullptr, nullptr, 0);
    {
        struct Run { int g; _Float16* E; int wi; };
        Run runs[2] = {{2, E3, 2}, {3, E4, 3}};
        for (int r = 0; r < 2; ++r) {
            spmm128(runs[r].g, Abuf, enc_b0[1], Bbuf, nullptr, runs[r].E, ws_w + runs[r].wi * 3 + 0, 1);
            spmm128(runs[r].g, Bbuf, nullptr, XB, nullptr, nullptr, nullptr, 0);
            gemm128(XB, oEnc2W1, enc_b[1], 128, 0, Bbuf, nullptr, runs[r].E, ws_w + runs[r].wi * 3 + 1, 2);
            spmm128(runs[r].g, Bbuf, nullptr, XB, nullptr, nullptr, nullptr, 0);
            gemm128(XB, oEnc2W2, enc_b[1] + 128, 128, 0, nullptr, nullptr, runs[r].E, ws_w + runs[r].wi * 3 + 2, 2);
        }
    }

    // ---- Stage D: attentions ----
    gemm128(E1, oAtt1, nullptr, 128, 1, V1, nullptr, nullptr, nullptr, 0);
    gemm128(E2, oAtt1, nullptr, 128, 1, V2, nullptr, nullptr, nullptr, 0);
    afin(E1, E2, V1, V2, att_u[0], O_emb1, emb1_16, nullptr);
    gemm128(E3, oAtt2, nullptr, 128, 1, V1, nullptr, nullptr, nullptr, 0);
    gemm128(E4, oAtt2, nullptr, 128, 1, V2, nullptr, nullptr, nullptr, 0);
    afin(E3, E4, V1, V2, att_u[1], O_emb2, emb2_16, nullptr);
    gemm128(emb1_16, oAttc, nullptr, 128, 1, V1, nullptr, nullptr, nullptr, 0);
    gemm128(emb2_16, oAttc, nullptr, 128, 1, V2, nullptr, nullptr, nullptr, 0);
    afin(emb1_16, emb2_16, V1, V2, att_u[2], O_embc, embc16, O_alph);

    // ---- Stage E: decoders d1, d2 (graph 0, shared first aggregation) ----
    spmm128(0, embc16, nullptr, Abuf, nullptr, nullptr, nullptr, 0);  // agg0
    for (int dsel = 0; dsel < 2; ++dsel) {
        float* od = (dsel == 0) ? O_d1 : O_d2;
        gemm128(Abuf, oDecW0[dsel], dec_b0[dsel], 256, 0, Bbuf, nullptr, nullptr, nullptr, 0);
        spmm256(0, Bbuf, Xe);
        gemm256(Xe, oDecW1[dsel], dec_b[dsel], 256, 0, Bbuf, nullptr, nullptr, nullptr, 0);
        spmm256(0, Bbuf, Xe);
        gemm256(Xe, oDecW2[dsel], dec_b[dsel] + 256, 256, 0, nullptr, od, nullptr, nullptr, 0);
    }

    // ---- Stage F: cross1 = enc2(g0, dec2(g0, emb1)); cross2 = enc1(g2, dec1(g2, emb2)) ----
    for (int c = 0; c < 2; ++c) {
        const int g = (c == 0) ? 0 : 2;
        const int dsel = (c == 0) ? 1 : 0;
        const int enc = (c == 0) ? 1 : 0;
        const _Float16* inp = (c == 0) ? emb1_16 : emb2_16;
        float* oc = (c == 0) ? O_c1 : O_c2;
        // decoder
        spmm128(g, inp, nullptr, Abuf, nullptr, nullptr, nullptr, 0);
        gemm128(Abuf, oDecW0[dsel], dec_b0[dsel], 256, 0, Bbuf, nullptr, nullptr, nullptr, 0);
        spmm256(g, Bbuf, Abuf);
        gemm256(Abuf, oDecW1[dsel], dec_b[dsel], 256, 0, Bbuf, nullptr, nullptr, nullptr, 0);
        spmm256(g, Bbuf, Abuf);
        gemm256(Abuf, oDecW2[dsel], dec_b[dsel] + 256, 256, 0, Bbuf, nullptr, nullptr, nullptr, 0);
        // encoder (project-first L1), stack written to output
        gemm256(Bbuf, oEncW0[enc], nullptr, 128, 0, Abuf, nullptr, nullptr, nullptr, 0);
        spmm128(g, Abuf, enc_b0[enc], Bbuf, oc, nullptr, nullptr, 0);
        spmm128(g, Bbuf, nullptr, Abuf, nullptr, nullptr, nullptr, 0);
        gemm128(Abuf, oEncW1[enc], enc_b[enc], 128, 0, Bbuf, oc + 2560000, nullptr, nullptr, 0);
        spmm128(g, Bbuf, nullptr, Abuf, nullptr, nullptr, nullptr, 0);
        gemm128(Abuf, oEncW2[enc], enc_b[enc] + 128, 128, 0, nullptr, oc + 5120000, nullptr, nullptr, 0);
    }
}

// Round 4
// 1858.870 us; speedup vs baseline: 1.5354x; 1.1655x over previous
//
#include <hip/hip_runtime.h>
#include <math.h>

#define NN 20000
#define NE 320000

typedef _Float16 v8h __attribute__((ext_vector_type(8)));
typedef _Float16 v4h __attribute__((ext_vector_type(4)));
typedef _Float16 v2h __attribute__((ext_vector_type(2)));
typedef float v4f __attribute__((ext_vector_type(4)));

// ---------------- CSR build ----------------

__global__ void k_zero_i32(int* __restrict__ p, int n) {
    int i = blockIdx.x * blockDim.x + threadIdx.x;
    if (i < n) p[i] = 0;
}

__global__ void k_count(const int* __restrict__ d0, const int* __restrict__ d1,
                        const int* __restrict__ d2, const int* __restrict__ d3,
                        int* __restrict__ cnt) {
    int i = blockIdx.x * blockDim.x + threadIdx.x;
    int g = i / NE, e = i - g * NE;
    const int* dp = (g == 0) ? d0 : (g == 1) ? d1 : (g == 2) ? d2 : d3;
    atomicAdd(&cnt[g * NN + dp[e]], 1);
}

__global__ void k_scan(const int* __restrict__ cnt, int* __restrict__ off,
                       float* __restrict__ iv) {
    const int g = blockIdx.x;
    const int* c = cnt + g * NN;
    int* o = off + g * (NN + 1);
    float* ivg = iv + g * NN;
    __shared__ int buf[1024];
    const int t = threadIdx.x;
    int carry = 0;
    for (int base = 0; base < NN; base += 1024) {
        int v = (base + t < NN) ? c[base + t] : 0;
        int run = v;
        buf[t] = run;
        __syncthreads();
        for (int s = 1; s < 1024; s <<= 1) {
            int add = (t >= s) ? buf[t - s] : 0;
            __syncthreads();
            run += add;
            buf[t] = run;
            __syncthreads();
        }
        if (base + t < NN) {
            o[base + t] = carry + run - v;
            ivg[base + t] = 1.0f / (float)(v + 1);
        }
        int tot = buf[1023];
        __syncthreads();
        carry += tot;
    }
    if (t == 0) o[NN] = carry;
}

__global__ void k_cursor(const int* __restrict__ off, int* __restrict__ cur) {
    int i = blockIdx.x * blockDim.x + threadIdx.x;
    if (i >= 4 * NN) return;
    int g = i / NN, n = i - g * NN;
    cur[i] = off[g * (NN + 1) + n];
}

__global__ void k_fill(const int* __restrict__ s0, const int* __restrict__ d0,
                       const int* __restrict__ s1, const int* __restrict__ d1,
                       const int* __restrict__ s2, const int* __restrict__ d2,
                       const int* __restrict__ s3, const int* __restrict__ d3,
                       int* __restrict__ cur, int* __restrict__ csr) {
    int i = blockIdx.x * blockDim.x + threadIdx.x;
    int g = i / NE, e = i - g * NE;
    const int* sp = (g == 0) ? s0 : (g == 1) ? s1 : (g == 2) ? s2 : s3;
    const int* dp = (g == 0) ? d0 : (g == 1) ? d1 : (g == 2) ? d2 : d3;
    int dst = dp[e];
    int p = atomicAdd(&cur[g * NN + dst], 1);
    csr[(size_t)g * NE + p] = sp[e];
}

// ---------------- small glue ----------------

__global__ void k_wt_softmax(const float* __restrict__ a, const float* __restrict__ b,
                             const float* __restrict__ c, const float* __restrict__ d,
                             float* __restrict__ wsm, float* __restrict__ owt) {
    int t = threadIdx.x;
    if (t >= 4) return;
    const float* p = (t == 0) ? a : (t == 1) ? b : (t == 2) ? c : d;
    float x0 = p[0], x1 = p[1], x2 = p[2];
    float m = fmaxf(x0, fmaxf(x1, x2));
    float e0 = expf(x0 - m), e1 = expf(x1 - m), e2 = expf(x2 - m);
    float inv = 1.0f / (e0 + e1 + e2);
    wsm[t * 3 + 0] = e0 * inv; wsm[t * 3 + 1] = e1 * inv; wsm[t * 3 + 2] = e2 * inv;
    owt[t * 3 + 0] = e0 * inv; owt[t * 3 + 1] = e1 * inv; owt[t * 3 + 2] = e2 * inv;
}

// f32 -> f16 for both feature arrays in one launch
__global__ void k_cvt16(const float* __restrict__ f1, const float* __restrict__ f2,
                        _Float16* __restrict__ o1, _Float16* __restrict__ o2, int n4) {
    int i = blockIdx.x * blockDim.x + threadIdx.x;
    if (i >= 2 * n4) return;
    const float* in = (i < n4) ? f1 : f2;
    _Float16* out = (i < n4) ? o1 : o2;
    int j = (i < n4) ? i : i - n4;
    float4 v = ((const float4*)in)[j];
    v4h o; o[0] = (_Float16)v.x; o[1] = (_Float16)v.y; o[2] = (_Float16)v.z; o[3] = (_Float16)v.w;
    ((v4h*)out)[j] = o;
}

// ---------------- weight prep: transpose [K][N] f32 -> [N][K] f16 ----------------

struct PWArgs { const float* s[15]; };

__global__ __launch_bounds__(256) void k_prepW(PWArgs pa, _Float16* __restrict__ dst) {
    const int wK[15]   = {256,128,128,256,128,128, 128,256,256, 128,256,256, 128,128,128};
    const int wN[15]   = {128,128,128,128,128,128, 256,256,256, 256,256,256, 128,128,128};
    const int wOff[15] = {0,32768,49152,65536,98304,114688,
                          131072,163840,229376, 294912,327680,393216,
                          458752,475136,491520};
    int b = blockIdx.x, w = 0, start = 0;
    for (w = 0; w < 15; ++w) {
        int t = (wK[w] / 64) * (wN[w] / 64);
        if (b < start + t) break;
        start += t;
    }
    const int K = wK[w], N = wN[w];
    const int lt = b - start;
    const int nt = N / 64;
    const int k0 = (lt / nt) * 64, n0 = (lt % nt) * 64;
    const float* src = pa.s[w];
    __shared__ float T[64][65];
    const int t = threadIdx.x;
    const int c4 = (t & 15) * 4;
#pragma unroll
    for (int j = 0; j < 4; ++j) {
        int row = (t >> 4) + 16 * j;  // k-dim
        float4 v = *(const float4*)(src + (size_t)(k0 + row) * N + n0 + c4);
        T[row][c4 + 0] = v.x; T[row][c4 + 1] = v.y; T[row][c4 + 2] = v.z; T[row][c4 + 3] = v.w;
    }
    __syncthreads();
#pragma unroll
    for (int j = 0; j < 4; ++j) {
        int r = (t >> 4) + 16 * j;  // n-dim
        v4h o;
#pragma unroll
        for (int i = 0; i < 4; ++i) o[i] = (_Float16)T[c4 + i][r];
        *(v4h*)(dst + wOff[w] + (size_t)(n0 + r) * K + k0 + c4) = o;
    }
}

// ---------------- fused aggregate (+ optional MFMA projection) ----------------
// Block = 32 nodes, 256 threads.
// Phase 1: agg[n] = (x[n] + sum_{j in N(n)} x[j]) * iv[n]  -> LDS (if Wt) or outputs.
// Phase 2 (Wt != null): C = agg @ Wt^T + bias; outputs o16/o32; optional E (+)= wsc*C.

template<int K, int NOUT>
__global__ __launch_bounds__(256) void k_ag(
        const int* __restrict__ off, const int* __restrict__ csr, const float* __restrict__ iv,
        const _Float16* __restrict__ x, const _Float16* __restrict__ Wt,
        const float* __restrict__ bias,
        _Float16* __restrict__ o16, float* __restrict__ o32,
        _Float16* __restrict__ E, const float* __restrict__ wsc, int emode) {
    __shared__ _Float16 As[32][K + 8];
    const int t = threadIdx.x, w = t >> 6, l = t & 63;
    const int r0 = blockIdx.x * 32;
    // ---- phase 1 ----
    {
        constexpr int LPN = (K == 128) ? 16 : 32;   // lanes per node
        constexpr int NPW = 64 / LPN;               // nodes in parallel per wave
        const int sub = l / LPN, c = l % LPN;       // v8h chunk index
#pragma unroll
        for (int r = 0; r < 8 / NPW; ++r) {
            const int node = r0 + w * 8 + r * NPW + sub;
            const int e0 = off[node], cnt = off[node + 1] - e0;
            float a[8];
            v8h s = *(const v8h*)(x + (size_t)node * K + c * 8);
#pragma unroll
            for (int j = 0; j < 8; ++j) a[j] = (float)s[j];
            for (int e = 0; e < cnt; ++e) {
                int idx = csr[e0 + e];
                v8h v = *(const v8h*)(x + (size_t)idx * K + c * 8);
#pragma unroll
                for (int j = 0; j < 8; ++j) a[j] += (float)v[j];
            }
            const float sc = iv[node];
#pragma unroll
            for (int j = 0; j < 8; ++j) a[j] *= sc;
            if (Wt == nullptr) {
                if (bias) {
#pragma unroll
                    for (int j = 0; j < 8; ++j) a[j] += bias[c * 8 + j];
                }
                if (o16) {
                    v8h o;
#pragma unroll
                    for (int j = 0; j < 8; ++j) o[j] = (_Float16)a[j];
                    *(v8h*)(o16 + (size_t)node * K + c * 8) = o;
                }
                if (o32) {
                    float4 u0, u1;
                    u0.x = a[0]; u0.y = a[1]; u0.z = a[2]; u0.w = a[3];
                    u1.x = a[4]; u1.y = a[5]; u1.z = a[6]; u1.w = a[7];
                    *(float4*)(o32 + (size_t)node * K + c * 8) = u0;
                    *(float4*)(o32 + (size_t)node * K + c * 8 + 4) = u1;
                }
                if (emode) {  // K must be 128 in E modes
                    const float wv = *wsc;
                    _Float16* ep = E + (size_t)node * 128 + c * 8;
                    v8h o;
                    if (emode == 1) {
#pragma unroll
                        for (int j = 0; j < 8; ++j) o[j] = (_Float16)(a[j] * wv);
                    } else {
                        v8h old = *(v8h*)ep;
#pragma unroll
                        for (int j = 0; j < 8; ++j) o[j] = (_Float16)((float)old[j] + a[j] * wv);
                    }
                    *(v8h*)ep = o;
                }
            } else {
                v8h o;
#pragma unroll
                for (int j = 0; j < 8; ++j) o[j] = (_Float16)a[j];
                *(v8h*)&As[w * 8 + r * NPW + sub][c * 8] = o;
            }
        }
    }
    if (Wt == nullptr) return;
    __syncthreads();
    // ---- phase 2: 32 x NOUT GEMM from LDS ----
    const int lr = l & 15, lg = l >> 4;
    constexpr int NF = NOUT / 64;               // n-fragments per wave (2 or 4)
    const int col0 = w * NF * 16;
    v4f acc[2][NF];
#pragma unroll
    for (int m = 0; m < 2; ++m)
#pragma unroll
        for (int n = 0; n < NF; ++n) acc[m][n] = (v4f){0.f, 0.f, 0.f, 0.f};
    const _Float16* Wb = Wt + (size_t)(col0 + lr) * K + 8 * lg;
#pragma unroll
    for (int ks = 0; ks < K / 32; ++ks) {
        v8h a0 = *(const v8h*)&As[lr][ks * 32 + 8 * lg];
        v8h a1 = *(const v8h*)&As[lr + 16][ks * 32 + 8 * lg];
        v8h b[NF];
#pragma unroll
        for (int n = 0; n < NF; ++n) b[n] = *(const v8h*)(Wb + (size_t)(16 * n) * K + ks * 32);
#pragma unroll
        for (int n = 0; n < NF; ++n) {
            acc[0][n] = __builtin_amdgcn_mfma_f32_16x16x32_f16(a0, b[n], acc[0][n], 0, 0, 0);
            acc[1][n] = __builtin_amdgcn_mfma_f32_16x16x32_f16(a1, b[n], acc[1][n], 0, 0, 0);
        }
    }
    const float wv = emode ? *wsc : 0.f;
#pragma unroll
    for (int m = 0; m < 2; ++m) {
#pragma unroll
        for (int n = 0; n < NF; ++n) {
            const int col = col0 + n * 16 + lr;
            const float bv = bias ? bias[col] : 0.f;
#pragma unroll
            for (int i = 0; i < 4; ++i) {
                const int row = r0 + m * 16 + 4 * lg + i;
                float v = acc[m][n][i] + bv;
                if (o16) o16[(size_t)row * NOUT + col] = (_Float16)v;
                if (o32) o32[(size_t)row * NOUT + col] = v;
                if (NOUT == 128 && emode) {
                    _Float16* ep = E + (size_t)row * 128 + col;
                    if (emode == 1) *ep = (_Float16)(v * wv);
                    else *ep = (_Float16)((float)*ep + v * wv);
                }
            }
        }
    }
}

// ---------------- pure MFMA GEMM (projections): C = A @ Wt^T + bias ----------------

template<int K>
__global__ __launch_bounds__(256) void k_gemm(const _Float16* __restrict__ A,
        const _Float16* __restrict__ Wt, const float* __restrict__ bias,
        int Ntot, _Float16* __restrict__ C16, float* __restrict__ C32) {
    const int wid = threadIdx.x >> 6, l = threadIdx.x & 63;
    const int r0 = (blockIdx.y * 4 + wid) * 32;
    if (r0 >= NN) return;
    const int colbase = blockIdx.x * 128;
    const int lr = l & 15, lg = l >> 4;
    v4f acc[2][8];
#pragma unroll
    for (int m = 0; m < 2; ++m)
#pragma unroll
        for (int n = 0; n < 8; ++n) acc[m][n] = (v4f){0.f, 0.f, 0.f, 0.f};
    const _Float16* Ab = A + (size_t)(r0 + lr) * K + 8 * lg;
    const _Float16* Wb = Wt + (size_t)(colbase + lr) * K + 8 * lg;
#pragma unroll
    for (int k = 0; k < K / 32; ++k) {
        v8h a0 = *(const v8h*)(Ab + k * 32);
        v8h a1 = *(const v8h*)(Ab + (size_t)16 * K + k * 32);
#pragma unroll
        for (int n = 0; n < 8; ++n) {
            v8h b = *(const v8h*)(Wb + (size_t)(16 * n) * K + k * 32);
            acc[0][n] = __builtin_amdgcn_mfma_f32_16x16x32_f16(a0, b, acc[0][n], 0, 0, 0);
            acc[1][n] = __builtin_amdgcn_mfma_f32_16x16x32_f16(a1, b, acc[1][n], 0, 0, 0);
        }
    }
#pragma unroll
    for (int m = 0; m < 2; ++m) {
#pragma unroll
        for (int n = 0; n < 8; ++n) {
            const int col = colbase + n * 16 + lr;
            const float bv = bias ? bias[col] : 0.f;
#pragma unroll
            for (int i = 0; i < 4; ++i) {
                const int row = r0 + m * 16 + 4 * lg + i;
                float v = acc[m][n][i] + bv;
                if (C16) C16[(size_t)row * Ntot + col] = (_Float16)v;
                if (C32) C32[(size_t)row * Ntot + col] = v;
            }
        }
    }
}

// ---------------- fully fused attention (both branches + softmax + combine) ----------------
// Block = 32 nodes. v = tanh(e @ W); vu = v @ u; alpha = softmax2(vu); out = a1*e1 + a2*e2.

__global__ __launch_bounds__(256) void k_attn(
        const _Float16* __restrict__ e1, const _Float16* __restrict__ e2,
        const _Float16* __restrict__ Wg, const float* __restrict__ u,
        float* __restrict__ o32, _Float16* __restrict__ o16, float* __restrict__ alpha) {
    __shared__ _Float16 Wl[128][136];
    __shared__ float pvu[2][4][32];
    __shared__ float als[32][2];
    const int t = threadIdx.x, w = t >> 6, l = t & 63;
    const int r0 = blockIdx.x * 32;
    for (int j = t; j < 2048; j += 256) {  // 128 rows x 16 v8h chunks
        int r = j >> 4, c = j & 15;
        *(v8h*)&Wl[r][c * 8] = *(const v8h*)(Wg + (size_t)r * 128 + c * 8);
    }
    __syncthreads();
    const int lr = l & 15, lg = l >> 4;
    const int col0 = w * 32;
    v4f acc1[2][2], acc2[2][2];
#pragma unroll
    for (int m = 0; m < 2; ++m)
#pragma unroll
        for (int n = 0; n < 2; ++n) { acc1[m][n] = (v4f){0,0,0,0}; acc2[m][n] = (v4f){0,0,0,0}; }
    const _Float16* A1 = e1 + (size_t)(r0 + lr) * 128 + 8 * lg;
    const _Float16* A2 = e2 + (size_t)(r0 + lr) * 128 + 8 * lg;
#pragma unroll
    for (int ks = 0; ks < 4; ++ks) {
        v8h a10 = *(const v8h*)(A1 + ks * 32);
        v8h a11 = *(const v8h*)(A1 + 16 * 128 + ks * 32);
        v8h a20 = *(const v8h*)(A2 + ks * 32);
        v8h a21 = *(const v8h*)(A2 + 16 * 128 + ks * 32);
        v8h b0 = *(const v8h*)&Wl[col0 + lr][ks * 32 + 8 * lg];
        v8h b1 = *(const v8h*)&Wl[col0 + 16 + lr][ks * 32 + 8 * lg];
        acc1[0][0] = __builtin_amdgcn_mfma_f32_16x16x32_f16(a10, b0, acc1[0][0], 0, 0, 0);
        acc1[0][1] = __builtin_amdgcn_mfma_f32_16x16x32_f16(a10, b1, acc1[0][1], 0, 0, 0);
        acc1[1][0] = __builtin_amdgcn_mfma_f32_16x16x32_f16(a11, b0, acc1[1][0], 0, 0, 0);
        acc1[1][1] = __builtin_amdgcn_mfma_f32_16x16x32_f16(a11, b1, acc1[1][1], 0, 0, 0);
        acc2[0][0] = __builtin_amdgcn_mfma_f32_16x16x32_f16(a20, b0, acc2[0][0], 0, 0, 0);
        acc2[0][1] = __builtin_amdgcn_mfma_f32_16x16x32_f16(a20, b1, acc2[0][1], 0, 0, 0);
        acc2[1][0] = __builtin_amdgcn_mfma_f32_16x16x32_f16(a21, b0, acc2[1][0], 0, 0, 0);
        acc2[1][1] = __builtin_amdgcn_mfma_f32_16x16x32_f16(a21, b1, acc2[1][1], 0, 0, 0);
    }
    const float uA = u[col0 + lr], uB = u[col0 + 16 + lr];
#pragma unroll
    for (int m = 0; m < 2; ++m)
#pragma unroll
        for (int i = 0; i < 4; ++i) {
            float q1 = tanhf(acc1[m][0][i]) * uA + tanhf(acc1[m][1][i]) * uB;
            float q2 = tanhf(acc2[m][0][i]) * uA + tanhf(acc2[m][1][i]) * uB;
#pragma unroll
            for (int s = 1; s < 16; s <<= 1) {
                q1 += __shfl_xor(q1, s, 64);
                q2 += __shfl_xor(q2, s, 64);
            }
            if (lr == 0) {
                pvu[0][w][m * 16 + 4 * lg + i] = q1;
                pvu[1][w][m * 16 + 4 * lg + i] = q2;
            }
        }
    __syncthreads();
    if (t < 32) {
        float s1 = pvu[0][0][t] + pvu[0][1][t] + pvu[0][2][t] + pvu[0][3][t];
        float s2 = pvu[1][0][t] + pvu[1][1][t] + pvu[1][2][t] + pvu[1][3][t];
        float mx = fmaxf(s1, s2);
        float q1 = expf(s1 - mx), q2 = expf(s2 - mx);
        float inv = 1.0f / (q1 + q2);
        als[t][0] = q1 * inv; als[t][1] = q2 * inv;
        if (alpha) {
            alpha[(size_t)(r0 + t) * 2 + 0] = q1 * inv;
            alpha[(size_t)(r0 + t) * 2 + 1] = q2 * inv;
        }
    }
    __syncthreads();
    {
        // 8 threads per row; each thread covers 2 x v8h = 16 elements -> full 128 cols
        const int row = t >> 3, c8 = t & 7;
        const float a1v = als[row][0], a2v = als[row][1];
#pragma unroll
        for (int half = 0; half < 2; ++half) {
            const int cc = c8 + half * 8;
            v8h x1 = *(const v8h*)(e1 + (size_t)(r0 + row) * 128 + cc * 8);
            v8h x2 = *(const v8h*)(e2 + (size_t)(r0 + row) * 128 + cc * 8);
            float o[8];
#pragma unroll
            for (int j = 0; j < 8; ++j) o[j] = a1v * (float)x1[j] + a2v * (float)x2[j];
            float4 u0, u1;
            u0.x = o[0]; u0.y = o[1]; u0.z = o[2]; u0.w = o[3];
            u1.x = o[4]; u1.y = o[5]; u1.z = o[6]; u1.w = o[7];
            *(float4*)(o32 + (size_t)(r0 + row) * 128 + cc * 8) = u0;
            *(float4*)(o32 + (size_t)(r0 + row) * 128 + cc * 8 + 4) = u1;
            v8h oh;
#pragma unroll
            for (int j = 0; j < 8; ++j) oh[j] = (_Float16)o[j];
            *(v8h*)(o16 + (size_t)(r0 + row) * 128 + cc * 8) = oh;
        }
    }
}

// ---------------- host ----------------

static inline char* alignup(char* p, size_t a) {
    return (char*)(((uintptr_t)p + a - 1) & ~(uintptr_t)(a - 1));
}

extern "C" void kernel_launch(void* const* d_in, const int* in_sizes, int n_in,
                              void* d_out, int out_size, void* d_ws, size_t ws_size,
                              hipStream_t stream) {
    (void)in_sizes; (void)n_in; (void)out_size; (void)ws_size;
    const int* esrc[4] = {(const int*)d_in[0], (const int*)d_in[2], (const int*)d_in[4], (const int*)d_in[6]};
    const int* edst[4] = {(const int*)d_in[1], (const int*)d_in[3], (const int*)d_in[5], (const int*)d_in[7]};
    const float* feat1 = (const float*)d_in[8];
    const float* feat2 = (const float*)d_in[9];
    const float* enc_W0[2] = {(const float*)d_in[10], (const float*)d_in[14]};
    const float* enc_b0[2] = {(const float*)d_in[11], (const float*)d_in[15]};
    const float* enc_W[2]  = {(const float*)d_in[12], (const float*)d_in[16]};
    const float* enc_b[2]  = {(const float*)d_in[13], (const float*)d_in[17]};
    const float* dec_W0[2] = {(const float*)d_in[18], (const float*)d_in[22]};
    const float* dec_b0[2] = {(const float*)d_in[19], (const float*)d_in[23]};
    const float* dec_W[2]  = {(const float*)d_in[20], (const float*)d_in[24]};
    const float* dec_b[2]  = {(const float*)d_in[21], (const float*)d_in[25]};
    const float* att_w[3]  = {(const float*)d_in[26], (const float*)d_in[28], (const float*)d_in[30]};
    const float* att_u[3]  = {(const float*)d_in[27], (const float*)d_in[29], (const float*)d_in[31]};
    const float* wt[4]     = {(const float*)d_in[32], (const float*)d_in[33], (const float*)d_in[34], (const float*)d_in[35]};

    float* out = (float*)d_out;
    float* O_embc = out;                    // [N,128]
    float* O_wt   = out + 2560000;          // [4,3]
    float* O_d1   = out + 2560012;          // [N,256]
    float* O_d2   = out + 7680012;          // [N,256]
    float* O_emb1 = out + 12800012;         // [N,128]
    float* O_emb2 = out + 15360012;         // [N,128]
    float* O_c1   = out + 17920012;         // [3,N,128]
    float* O_c2   = out + 25600012;         // [3,N,128]
    float* O_alph = out + 33280012;         // [N,2]

    // f16 temporaries in dead output regions (stages B-E only)
    _Float16* E1 = (_Float16*)O_c1;                 // e_sp1
    _Float16* E2 = E1 + (size_t)NN * 128;           // e_fe1
    _Float16* E3 = E2 + (size_t)NN * 128;           // e_sp2
    _Float16* E4 = E3 + (size_t)NN * 128;           // e_fe2
    _Float16* Xe = (_Float16*)O_c2;                 // stage-E [N,256] scratch (dead until F c=1)

    // workspace
    char* wp = (char*)d_ws;
    int* ws_off = (int*)wp;    wp += (size_t)4 * (NN + 1) * sizeof(int); wp = alignup(wp, 64);
    int* ws_csr = (int*)wp;    wp += (size_t)4 * NE * sizeof(int);
    int* ws_cur = (int*)wp;    wp += (size_t)4 * NN * sizeof(int);
    float* ws_iv = (float*)wp; wp += (size_t)4 * NN * sizeof(float);
    float* ws_w  = (float*)wp; wp += 64;
    _Float16* Wt = (_Float16*)wp; wp += (size_t)507904 * 2; wp = alignup(wp, 64);
    _Float16* F1 = (_Float16*)wp; wp += (size_t)NN * 256 * 2;
    _Float16* F2 = (_Float16*)wp; wp += (size_t)NN * 256 * 2;
    _Float16* Abuf = (_Float16*)wp; wp += (size_t)NN * 256 * 2;
    _Float16* Bbuf = (_Float16*)wp; wp += (size_t)NN * 256 * 2;

    _Float16* XB = F1;                          // stage-B scratch (feat1 f16 dead after P1)
    _Float16* embc16 = F1;                      // stage D+: F1 free
    _Float16* emb1_16 = F1 + (size_t)NN * 128;
    _Float16* emb2_16 = F2;

    // Wt segment offsets (elements)
    const int oEnc1W0 = 0, oEnc1W1 = 32768, oEnc1W2 = 49152;
    const int oEnc2W0 = 65536, oEnc2W1 = 98304, oEnc2W2 = 114688;
    const int oDec1W0 = 131072, oDec1W1 = 163840, oDec1W2 = 229376;
    const int oDec2W0 = 294912, oDec2W1 = 327680, oDec2W2 = 393216;
    const int oAtt1 = 458752, oAtt2 = 475136, oAttc = 491520;
    const int oEncW0[2] = {oEnc1W0, oEnc2W0};
    const int oEncW1[2] = {oEnc1W1, oEnc2W1};
    const int oEncW2[2] = {oEnc1W2, oEnc2W2};
    const int oDecW0[2] = {oDec1W0, oDec2W0};
    const int oDecW1[2] = {oDec1W1, oDec2W1};
    const int oDecW2[2] = {oDec1W2, oDec2W2};

    // ---- CSR build ----
    hipLaunchKernelGGL(k_zero_i32, dim3(313), dim3(256), 0, stream, ws_cur, 4 * NN);
    hipLaunchKernelGGL(k_count, dim3(5000), dim3(256), 0, stream,
                       edst[0], edst[1], edst[2], edst[3], ws_cur);
    hipLaunchKernelGGL(k_scan, dim3(4), dim3(1024), 0, stream, ws_cur, ws_off, ws_iv);
    hipLaunchKernelGGL(k_cursor, dim3(313), dim3(256), 0, stream, ws_off, ws_cur);
    hipLaunchKernelGGL(k_fill, dim3(5000), dim3(256), 0, stream,
                       esrc[0], edst[0], esrc[1], edst[1], esrc[2], edst[2], esrc[3], edst[3],
                       ws_cur, ws_csr);
    hipLaunchKernelGGL(k_wt_softmax, dim3(1), dim3(64), 0, stream,
                       wt[0], wt[1], wt[2], wt[3], ws_w, O_wt);

    // ---- weight + feature conversion ----
    PWArgs pa;
    pa.s[0] = enc_W0[0]; pa.s[1] = enc_W[0]; pa.s[2] = enc_W[0] + 16384;
    pa.s[3] = enc_W0[1]; pa.s[4] = enc_W[1]; pa.s[5] = enc_W[1] + 16384;
    pa.s[6] = dec_W0[0]; pa.s[7] = dec_W[0]; pa.s[8] = dec_W[0] + 65536;
    pa.s[9] = dec_W0[1]; pa.s[10] = dec_W[1]; pa.s[11] = dec_W[1] + 65536;
    pa.s[12] = att_w[0]; pa.s[13] = att_w[1]; pa.s[14] = att_w[2];
    hipLaunchKernelGGL(k_prepW, dim3(124), dim3(256), 0, stream, pa, Wt);
    hipLaunchKernelGGL(k_cvt16, dim3(10000), dim3(256), 0, stream, feat1, feat2, F1, F2, NN * 64);

    // launch helpers
    auto ag128 = [&](int g, const _Float16* x, int wtoff, const float* bias,
                     _Float16* o16, float* o32, _Float16* E, const float* wsc, int em) {
        hipLaunchKernelGGL((k_ag<128, 128>), dim3(625), dim3(256), 0, stream,
                           ws_off + g * (NN + 1), ws_csr + (size_t)g * NE, ws_iv + g * NN,
                           x, (wtoff >= 0) ? Wt + wtoff : nullptr, bias, o16, o32, E, wsc, em);
    };
    auto ag128x256 = [&](int g, const _Float16* x, int wtoff, const float* bias, _Float16* o16) {
        hipLaunchKernelGGL((k_ag<128, 256>), dim3(625), dim3(256), 0, stream,
                           ws_off + g * (NN + 1), ws_csr + (size_t)g * NE, ws_iv + g * NN,
                           x, Wt + wtoff, bias, o16, nullptr, nullptr, nullptr, 0);
    };
    auto ag256 = [&](int g, const _Float16* x, int wtoff, const float* bias,
                     _Float16* o16, float* o32) {
        hipLaunchKernelGGL((k_ag<256, 256>), dim3(625), dim3(256), 0, stream,
                           ws_off + g * (NN + 1), ws_csr + (size_t)g * NE, ws_iv + g * NN,
                           x, Wt + wtoff, bias, o16, o32, nullptr, nullptr, 0);
    };
    auto gemm = [&](int K, const _Float16* A, int wtoff, const float* bias, int Ntot,
                    _Float16* C16, float* C32) {
        if (K == 128)
            hipLaunchKernelGGL(k_gemm<128>, dim3(Ntot / 128, 157), dim3(256), 0, stream,
                               A, Wt + wtoff, bias, Ntot, C16, C32);
        else
            hipLaunchKernelGGL(k_gemm<256>, dim3(Ntot / 128, 157), dim3(256), 0, stream,
                               A, Wt + wtoff, bias, Ntot, C16, C32);
    };
    auto attn = [&](const _Float16* x1, const _Float16* x2, int wtoff, const float* uu,
                    float* eo32, _Float16* eo16, float* al) {
        hipLaunchKernelGGL(k_attn, dim3(625), dim3(256), 0, stream,
                           x1, x2, Wt + wtoff, uu, eo32, eo16, al);
    };

    // ---- Stage B: encoders (project-first L1, fused agg+proj L2/L3, fused combine) ----
    gemm(256, F1, oEnc1W0, nullptr, 128, Abuf, nullptr);   // P1 (shared g0,g1)
    for (int r = 0; r < 2; ++r) {
        _Float16* Er = (r == 0) ? E1 : E2;
        const float* w3 = ws_w + r * 3;
        ag128(r, Abuf, -1, enc_b0[0], Bbuf, nullptr, Er, w3 + 0, 1);
        ag128(r, Bbuf, oEnc1W1, enc_b[0], XB, nullptr, Er, w3 + 1, 2);
        ag128(r, XB, oEnc1W2, enc_b[0] + 128, nullptr, nullptr, Er, w3 + 2, 2);
    }
    gemm(256, F2, oEnc2W0, nullptr, 128, Abuf, nullptr);   // P2 (shared g2,g3)
    for (int r = 0; r < 2; ++r) {
        _Float16* Er = (r == 0) ? E3 : E4;
        const float* w3 = ws_w + (2 + r) * 3;
        ag128(2 + r, Abuf, -1, enc_b0[1], Bbuf, nullptr, Er, w3 + 0, 1);
        ag128(2 + r, Bbuf, oEnc2W1, enc_b[1], XB, nullptr, Er, w3 + 1, 2);
        ag128(2 + r, XB, oEnc2W2, enc_b[1] + 128, nullptr, nullptr, Er, w3 + 2, 2);
    }

    // ---- Stage D: attentions (fully fused) ----
    attn(E1, E2, oAtt1, att_u[0], O_emb1, emb1_16, nullptr);
    attn(E3, E4, oAtt2, att_u[1], O_emb2, emb2_16, nullptr);
    attn(emb1_16, emb2_16, oAttc, att_u[2], O_embc, embc16, O_alph);

    // ---- Stage E: decoders d1, d2 (graph 0, shared first aggregation) ----
    ag128(0, embc16, -1, nullptr, Abuf, nullptr, nullptr, nullptr, 0);  // agg0
    for (int dsel = 0; dsel < 2; ++dsel) {
        float* od = (dsel == 0) ? O_d1 : O_d2;
        gemm(128, Abuf, oDecW0[dsel], dec_b0[dsel], 256, Bbuf, nullptr);
        ag256(0, Bbuf, oDecW1[dsel], dec_b[dsel], Xe, nullptr);
        ag256(0, Xe, oDecW2[dsel], dec_b[dsel] + 256, nullptr, od);
    }

    // ---- Stage F: cross1 = enc2(g0, dec2(g0, emb1)); cross2 = enc1(g2, dec1(g2, emb2)) ----
    for (int c = 0; c < 2; ++c) {
        const int g = (c == 0) ? 0 : 2;
        const int dsel = (c == 0) ? 1 : 0;
        const int enc = (c == 0) ? 1 : 0;
        const _Float16* inp = (c == 0) ? emb1_16 : emb2_16;
        float* oc = (c == 0) ? O_c1 : O_c2;
        // decoder (fused agg+proj each layer)
        ag128x256(g, inp, oDecW0[dsel], dec_b0[dsel], Bbuf);
        ag256(g, Bbuf, oDecW1[dsel], dec_b[dsel], Abuf, nullptr);
        ag256(g, Abuf, oDecW2[dsel], dec_b[dsel] + 256, Bbuf, nullptr);
        // encoder stack (project-first L1), written straight to outputs
        gemm(256, Bbuf, oEncW0[enc], nullptr, 128, Abuf, nullptr);
        ag128(g, Abuf, -1, enc_b0[enc], Bbuf, oc, nullptr, nullptr, 0);
        ag128(g, Bbuf, oEncW1[enc], enc_b[enc], Abuf, oc + 2560000, nullptr, nullptr, 0);
        ag128(g, Abuf, oEncW2[enc], enc_b[enc] + 128, nullptr, oc + 5120000, nullptr, nullptr, 0);
    }
}